// Round 15
// baseline (249.662 us; speedup 1.0000x reference)
//
#include <hip/hip_runtime.h>

typedef unsigned short u16;
typedef unsigned int u32;
typedef __bf16 bf16x8 __attribute__((ext_vector_type(8)));
typedef float f32x4 __attribute__((ext_vector_type(4)));

#define AS1 __attribute__((address_space(1)))
#define AS3 __attribute__((address_space(3)))

// XOR-swizzle for 128B-row LDS tiles (T2): flips byte bits 4-6 with row&7
#define SWZB(x) ((x) ^ ((((x) >> 7) & 7) << 4))

__device__ __forceinline__ float bf2f(u16 u) {
    union { u32 i; float f; } v; v.i = ((u32)u) << 16; return v.f;
}
__device__ __forceinline__ u16 f2bf(float f) {
    union { float f; u32 i; } v; v.f = f;
    u32 i = v.i;
    u32 r = (i + 0x7fffu + ((i >> 16) & 1u)) >> 16;
    return (u16)r;
}
// unpack a u32 holding two bf16: low elem -> f32, high elem -> f32
__device__ __forceinline__ float blo(u32 u) {
    union { u32 i; float f; } v; v.i = u << 16; return v.f;
}
__device__ __forceinline__ float bhi(u32 u) {
    union { u32 i; float f; } v; v.i = u & 0xFFFF0000u; return v.f;
}
__device__ __forceinline__ u32 cvtpk_bf16(float lo, float hi) {
    u32 r;
    asm("v_cvt_pk_bf16_f32 %0, %1, %2" : "=v"(r) : "v"(lo), "v"(hi));
    return r;
}
// raw 2^x (v_exp_f32); log2e pre-folded into Wq so softmax = exp2(s*m)
__device__ __forceinline__ float fexp2(float x) {
    float r;
    asm("v_exp_f32 %0, %1" : "=v"(r) : "v"(x));
    return r;
}
__device__ __forceinline__ void gload_lds16(const u16* src, u16* dst) {
    __builtin_amdgcn_global_load_lds((const AS1 void*)src, (AS3 void*)dst, 16, 0, 0);
}

// ---------------------------------------------------------------- transpose
// All 4 weight transposes in ONE launch (z selects source); fp32 -> bf16,
// out[j][i] = (bf16)(in[i][j]*scale). z=0: Wq*SCALE*log2e, z=1: Wk, z=2: Wv,
// z=3: Wo -> WoT.
__global__ __launch_bounds__(256) void transposeW(const float* __restrict__ Wq,
                                                  const float* __restrict__ Wk,
                                                  const float* __restrict__ Wv,
                                                  const float* __restrict__ Wo,
                                                  u16* __restrict__ WT,
                                                  u16* __restrict__ WoT) {
    __shared__ u16 t[64][65];
    int z = blockIdx.z;
    const float* in = (z == 0) ? Wq : (z == 1) ? Wk : (z == 2) ? Wv : Wo;
    u16* out = (z < 3) ? WT + (size_t)z * 1024 * 1024 : WoT;
    float scale = (z == 0) ? 0.18033688f : 1.0f;   // SCALE*log2e into Wq
    int c = threadIdx.x & 63, r0 = threadIdx.x >> 6;
    int ib = blockIdx.y * 64, jb = blockIdx.x * 64;
    #pragma unroll
    for (int r = r0; r < 64; r += 4)
        t[r][c] = f2bf(in[(size_t)(ib + r) * 1024 + jb + c] * scale);
    __syncthreads();
    #pragma unroll
    for (int r = r0; r < 64; r += 4) out[(size_t)(jb + r) * 1024 + ib + c] = t[c][r];
}

// ---------------------------------------------------------------- mask prep
// fp32 mask -> bf16 (halves the dominant attn cache-traffic term)
__global__ __launch_bounds__(256) void maskprep(const float* __restrict__ in,
                                                u16* __restrict__ out) {
    int i = blockIdx.x * 256 + threadIdx.x;
    float4 v = *(const float4*)&in[(size_t)i * 4];
    ushort4 o;
    o.x = f2bf(v.x); o.y = f2bf(v.y); o.z = f2bf(v.z); o.w = f2bf(v.w);
    *(ushort4*)&out[(size_t)i * 4] = o;
}

// ---------------------------------------------------------------- layernorm
__global__ __launch_bounds__(256) void ln_kernel(const float* __restrict__ x,
                                                 const float* __restrict__ g,
                                                 const float* __restrict__ bb,
                                                 u16* __restrict__ xn) {
    int row = blockIdx.x;
    int tid = threadIdx.x;
    const float* xr = x + (size_t)row * 1024;
    float4 v = *(const float4*)&xr[tid * 4];
    float f0 = v.x, f1 = v.y, f2 = v.z, f3 = v.w;
    float s = f0 + f1 + f2 + f3;
    float sq = f0 * f0 + f1 * f1 + f2 * f2 + f3 * f3;
    #pragma unroll
    for (int m = 1; m < 64; m <<= 1) { s += __shfl_xor(s, m, 64); sq += __shfl_xor(sq, m, 64); }
    __shared__ float red[8];
    int wid = tid >> 6, lane = tid & 63;
    if (lane == 0) { red[wid] = s; red[4 + wid] = sq; }
    __syncthreads();
    s = red[0] + red[1] + red[2] + red[3];
    sq = red[4] + red[5] + red[6] + red[7];
    float mu = s * (1.f / 1024.f);
    float var = sq * (1.f / 1024.f) - mu * mu;
    float rs = rsqrtf(var + 1e-5f);
    float4 gv = *(const float4*)&g[tid * 4];
    float4 bv = *(const float4*)&bb[tid * 4];
    ushort4 o;
    o.x = f2bf((f0 - mu) * rs * gv.x + bv.x);
    o.y = f2bf((f1 - mu) * rs * gv.y + bv.y);
    o.z = f2bf((f2 - mu) * rs * gv.z + bv.z);
    o.w = f2bf((f3 - mu) * rs * gv.w + bv.w);
    *(ushort4*)&xn[(size_t)row * 1024 + tid * 4] = o;
}

// ---------------------------------------------------------------- GEMM (B^T)
// C[m][n] = sum_k A[m][k]*BT[n][k]; ext=0: bf16 out; ext=1: fp32 out + bias.
// vTout != nullptr: V-column blocks (n0 >= 2048) write TRANSPOSED to
// vT[(b*1024 + (col-2048)) * 2048 + t] (fused vtrans); Q,K go to C16 with
// ldc (=2048: V-third of qkvb eliminated).
// 1D grid with XCD-slab swizzle (T1).
__global__ __launch_bounds__(256) void gemm_bt(const u16* __restrict__ A,
                                               const u16* __restrict__ BT,
                                               u16* __restrict__ C16,
                                               float* __restrict__ C32,
                                               const float* __restrict__ bias,
                                               int K, int ldc, int ext, int nbx,
                                               u16* __restrict__ vTout) {
    __shared__ __align__(16) u16 lA[128 * 32];
    __shared__ __align__(16) u16 lB[128 * 32];
    int bid = blockIdx.x;
    int xcd = bid & 7, loc = bid >> 3;
    int npx = nbx >> 3;                  // n-blocks per XCD
    int n0 = (xcd * npx + loc % npx) * 128;
    int m0 = (loc / npx) * 128;
    int tid = threadIdx.x, lane = tid & 63, wid = tid >> 6;
    int wr = wid >> 1, wc = wid & 1;
    int l4 = lane >> 4, l15 = lane & 15;

    f32x4 acc[4][4] = {};
    int NT = K >> 5;

    auto stage = [&](int kt) {
        int k0 = kt << 5;
        #pragma unroll
        for (int i = 0; i < 2; ++i) {
            int j = wid * 2 + i;
            int row = j * 16 + (lane >> 2);
            int ch = (lane & 3) * 8;
            gload_lds16(A + (size_t)(m0 + row) * K + k0 + ch, &lA[j * 512]);
            gload_lds16(BT + (size_t)(n0 + row) * K + k0 + ch, &lB[j * 512]);
        }
    };
    stage(0);
    for (int kt = 0; kt < NT; ++kt) {
        __syncthreads();
        bf16x8 af[4], bfr[4];
        #pragma unroll
        for (int i = 0; i < 4; ++i) {
            af[i]  = *(const bf16x8*)&lA[(wr * 64 + i * 16 + l15) * 32 + l4 * 8];
            bfr[i] = *(const bf16x8*)&lB[(wc * 64 + i * 16 + l15) * 32 + l4 * 8];
        }
        __syncthreads();
        if (kt + 1 < NT) stage(kt + 1);
        #pragma unroll
        for (int i = 0; i < 4; ++i)
            #pragma unroll
            for (int j = 0; j < 4; ++j)
                acc[i][j] = __builtin_amdgcn_mfma_f32_16x16x32_bf16(af[i], bfr[j], acc[i][j], 0, 0, 0);
    }
    bool vblk = (vTout != nullptr) && (n0 >= 2048);
    #pragma unroll
    for (int j = 0; j < 4; ++j) {
        int col = n0 + wc * 64 + j * 16 + l15;
        if (vblk) {
            int hd = col - 2048;
            #pragma unroll
            for (int i = 0; i < 4; ++i) {
                int trow = m0 + wr * 64 + i * 16 + l4 * 4;   // 4 consecutive t
                int bidx = trow >> 11, t = trow & 2047;
                ushort4 pk;
                pk.x = f2bf(acc[i][j][0]);
                pk.y = f2bf(acc[i][j][1]);
                pk.z = f2bf(acc[i][j][2]);
                pk.w = f2bf(acc[i][j][3]);
                *(ushort4*)&vTout[(size_t)(bidx * 1024 + hd) * 2048 + t] = pk;
            }
        } else {
            float bv = ext ? bias[col] : 0.f;
            #pragma unroll
            for (int i = 0; i < 4; ++i) {
                #pragma unroll
                for (int r = 0; r < 4; ++r) {
                    int row = m0 + wr * 64 + i * 16 + l4 * 4 + r;
                    float val = acc[i][j][r] + bv;
                    if (ext) C32[(size_t)row * ldc + col] = val;
                    else     C16[(size_t)row * ldc + col] = f2bf(val);
                }
            }
        }
    }
}

// ---------------------------------------------------------------- attention
// R14 structure with K/V staging moved to global_load_lds DMA:
// linear LDS dest + (pmap . SWZB)-inverse applied to the per-lane GLOBAL
// source address (rule #21 / m173 pattern). Physical LDS bytes identical to
// R14 -> read path unchanged, arithmetic bit-identical. Loads issued at top
// of tile body, drained by the end-of-tile barrier (full-body latency cover).
__global__ __launch_bounds__(256) void attn_kernel(const u16* __restrict__ qkv,
                                                   const u16* __restrict__ vT,
                                                   const u16* __restrict__ maskb,
                                                   u16* __restrict__ av) {
    __shared__ __align__(16) u16 lK[2][64 * 64];   // [kv][dh], rows permuted+swizzled
    __shared__ __align__(16) u16 lV[2][64 * 64];   // [dh][kv], swizzled
    int qt = blockIdx.x, bh = blockIdx.y;
    int b = bh >> 4, h = bh & 15;
    int tid = threadIdx.x, lane = tid & 63, wid = tid >> 6;
    int l4 = lane >> 4, l15 = lane & 15;
    int qw = qt * 128 + wid * 32;      // this wave's 32 q-rows

    const u16* qb0 = qkv + (size_t)(b * 2048 + qw + l15) * 2048 + h * 64;
    const u16* qb1 = qb0 + (size_t)16 * 2048;
    bf16x8 qf00 = *(const bf16x8*)&qb0[l4 * 8];
    bf16x8 qf01 = *(const bf16x8*)&qb0[32 + l4 * 8];
    bf16x8 qf10 = *(const bf16x8*)&qb1[l4 * 8];
    bf16x8 qf11 = *(const bf16x8*)&qb1[32 + l4 * 8];
    const u16* mrow0 = maskb + (size_t)(qw + l15) * 2048 + 8 * l4;
    const u16* mrow1 = mrow0 + (size_t)16 * 2048;

    f32x4 o0[4] = {}, o1[4] = {};
    float lsum0 = 0.f, lsum1 = 0.f;

    // Staging: physical chunk c (16B at byte c*16, linear) must hold logical
    // u = SWZB(c*16): K row pinv(u>>7) chunk (u>>4)&7; V row u>>7 same chunk.
    // pmap bit-map (p5..p0)=(g5,g2,g4,g3,g1,g0) -> pinv(p)=(p5,p3,p2,p4,p1,p0).
    int c0 = tid, c1 = 256 + tid;
    auto pinv = [](int p) {
        return (p & 35) | ((p & 8) << 1) | ((p & 4) << 1) | ((p & 16) >> 2);
    };
    int u0 = SWZB(c0 * 16), u1 = SWZB(c1 * 16);
    int kr0 = pinv(u0 >> 7), kr1 = pinv(u1 >> 7);
    int vr0 = u0 >> 7,       vr1 = u1 >> 7;
    int ch0 = (u0 >> 4) & 7, ch1 = (u1 >> 4) & 7;
    const u16* kap0 = qkv + (size_t)(b * 2048 + kr0) * 2048 + 1024 + h * 64 + ch0 * 8;
    const u16* kap1 = qkv + (size_t)(b * 2048 + kr1) * 2048 + 1024 + h * 64 + ch1 * 8;
    const u16* vap0 = vT + (size_t)(bh * 64 + vr0) * 2048 + ch0 * 8;
    const u16* vap1 = vT + (size_t)(bh * 64 + vr1) * 2048 + ch1 * 8;

    // wave-uniform LDS dest bases (HW adds lane*16): c0 block -> wid*512 u16,
    // c1 block -> 2048 + wid*512 u16.
    auto stage = [&](int t, int buf) {
        size_t ko = (size_t)t * (64 * 2048);
        int vo = t * 64;
        gload_lds16(kap0 + ko, &lK[buf][wid * 512]);
        gload_lds16(kap1 + ko, &lK[buf][2048 + wid * 512]);
        gload_lds16(vap0 + vo, &lV[buf][wid * 512]);
        gload_lds16(vap1 + vo, &lV[buf][2048 + wid * 512]);
    };

    union PU { u32 u[4]; bf16x8 v; };

    stage(0, 0);
    __syncthreads();   // tile 0 staged & visible
    for (int t = 0; t < 32; ++t) {
        int pbuf = t & 1;
        // issue next tile's DMA into the other buffer: its previous readers
        // (body t-1) passed the last barrier; it drains at this tile's barrier.
        if (t + 1 < 32) stage(t + 1, pbuf ^ 1);
        int k0 = t * 64;
        // bf16 mask loads for this tile: 2x16B per q-frag (cover under QK^T)
        uint4 mua0 = *(const uint4*)(mrow0 + k0);        // cols 8l4+0..7
        uint4 mub0 = *(const uint4*)(mrow0 + k0 + 32);   // cols 8l4+32..39
        uint4 mua1 = *(const uint4*)(mrow1 + k0);
        uint4 mub1 = *(const uint4*)(mrow1 + k0 + 32);
        f32x4 mm0[4], mm1[4];
        mm0[0] = f32x4{blo(mua0.x), bhi(mua0.x), blo(mua0.y), bhi(mua0.y)};
        mm0[1] = f32x4{blo(mua0.z), bhi(mua0.z), blo(mua0.w), bhi(mua0.w)};
        mm0[2] = f32x4{blo(mub0.x), bhi(mub0.x), blo(mub0.y), bhi(mub0.y)};
        mm0[3] = f32x4{blo(mub0.z), bhi(mub0.z), blo(mub0.w), bhi(mub0.w)};
        mm1[0] = f32x4{blo(mua1.x), bhi(mua1.x), blo(mua1.y), bhi(mua1.y)};
        mm1[1] = f32x4{blo(mua1.z), bhi(mua1.z), blo(mua1.w), bhi(mua1.w)};
        mm1[2] = f32x4{blo(mub1.x), bhi(mub1.x), blo(mub1.y), bhi(mub1.y)};
        mm1[3] = f32x4{blo(mub1.z), bhi(mub1.z), blo(mub1.w), bhi(mub1.w)};
        // S = mfma(K, Q)
        const char* Kb = (const char*)lK[pbuf];
        f32x4 s0[4] = {}, s1[4] = {};
        __builtin_amdgcn_s_setprio(1);
        #pragma unroll
        for (int fj = 0; fj < 4; ++fj) {
            bf16x8 kf0 = *(const bf16x8*)(Kb + SWZB((fj * 16 + l15) * 128 + l4 * 16));
            bf16x8 kf1 = *(const bf16x8*)(Kb + SWZB((fj * 16 + l15) * 128 + 64 + l4 * 16));
            s0[fj] = __builtin_amdgcn_mfma_f32_16x16x32_bf16(kf0, qf00, s0[fj], 0, 0, 0);
            s0[fj] = __builtin_amdgcn_mfma_f32_16x16x32_bf16(kf1, qf01, s0[fj], 0, 0, 0);
            s1[fj] = __builtin_amdgcn_mfma_f32_16x16x32_bf16(kf0, qf10, s1[fj], 0, 0, 0);
            s1[fj] = __builtin_amdgcn_mfma_f32_16x16x32_bf16(kf1, qf11, s1[fj], 0, 0, 0);
        }
        __builtin_amdgcn_s_setprio(0);
        // P = exp2(s*m) (SCALE*log2e in Q), packed into PV A-frags
        PU pa0[2], pa1[2];
        #pragma unroll
        for (int fj = 0; fj < 4; ++fj) {
            float p0 = fexp2(s0[fj][0] * mm0[fj][0]);
            float p1 = fexp2(s0[fj][1] * mm0[fj][1]);
            float p2 = fexp2(s0[fj][2] * mm0[fj][2]);
            float p3 = fexp2(s0[fj][3] * mm0[fj][3]);
            lsum0 += (p0 + p1) + (p2 + p3);
            int ks = fj >> 1, hf = (fj & 1) * 2;
            pa0[ks].u[hf]     = cvtpk_bf16(p0, p1);
            pa0[ks].u[hf + 1] = cvtpk_bf16(p2, p3);
        }
        #pragma unroll
        for (int fj = 0; fj < 4; ++fj) {
            float p0 = fexp2(s1[fj][0] * mm1[fj][0]);
            float p1 = fexp2(s1[fj][1] * mm1[fj][1]);
            float p2 = fexp2(s1[fj][2] * mm1[fj][2]);
            float p3 = fexp2(s1[fj][3] * mm1[fj][3]);
            lsum1 += (p0 + p1) + (p2 + p3);
            int ks = fj >> 1, hf = (fj & 1) * 2;
            pa1[ks].u[hf]     = cvtpk_bf16(p0, p1);
            pa1[ks].u[hf + 1] = cvtpk_bf16(p2, p3);
        }
        // O += P V
        const char* Vb = (const char*)lV[pbuf];
        __builtin_amdgcn_s_setprio(1);
        #pragma unroll
        for (int ks = 0; ks < 2; ++ks) {
            #pragma unroll
            for (int fj = 0; fj < 4; ++fj) {
                bf16x8 vf = *(const bf16x8*)(Vb + SWZB((fj * 16 + l15) * 128 + ks * 64 + l4 * 16));
                o0[fj] = __builtin_amdgcn_mfma_f32_16x16x32_bf16(pa0[ks].v, vf, o0[fj], 0, 0, 0);
                o1[fj] = __builtin_amdgcn_mfma_f32_16x16x32_bf16(pa1[ks].v, vf, o1[fj], 0, 0, 0);
            }
        }
        __builtin_amdgcn_s_setprio(0);
        __syncthreads();  // next tile's DMA drained & visible; buffers rotate
    }

    // rowsums: reduce over the 4 l4-groups (same q=l15 column)
    lsum0 += __shfl_xor(lsum0, 16, 64);
    lsum0 += __shfl_xor(lsum0, 32, 64);
    lsum1 += __shfl_xor(lsum1, 16, 64);
    lsum1 += __shfl_xor(lsum1, 32, 64);
    float den0[4], den1[4];
    #pragma unroll
    for (int r = 0; r < 4; ++r) {
        den0[r] = __shfl(lsum0, l4 * 4 + r, 64);
        den1[r] = __shfl(lsum1, l4 * 4 + r, 64);
    }
    #pragma unroll
    for (int fj = 0; fj < 4; ++fj) {
        #pragma unroll
        for (int r = 0; r < 4; ++r) {
            int col = h * 64 + fj * 16 + l15;
            av[(size_t)(b * 2048 + qw + l4 * 4 + r) * 1024 + col]      = f2bf(o0[fj][r] / den0[r]);
            av[(size_t)(b * 2048 + qw + 16 + l4 * 4 + r) * 1024 + col] = f2bf(o1[fj][r] / den1[r]);
        }
    }
}

// ---------------------------------------------------------------- launch
extern "C" void kernel_launch(void* const* d_in, const int* in_sizes, int n_in,
                              void* d_out, int out_size, void* d_ws, size_t ws_size,
                              hipStream_t stream) {
    (void)in_sizes; (void)n_in; (void)out_size; (void)ws_size;
    const float* x     = (const float*)d_in[0];
    const float* mask  = (const float*)d_in[1];
    const float* gamma = (const float*)d_in[2];
    const float* beta  = (const float*)d_in[3];
    const float* Wq    = (const float*)d_in[4];
    const float* Wk    = (const float*)d_in[5];
    const float* Wv    = (const float*)d_in[6];
    const float* Wo    = (const float*)d_in[7];
    const float* bo    = (const float*)d_in[8];

    char* ws = (char*)d_ws;
    u16* xn    = (u16*)(ws);                       // 16.8 MB (reused as av)
    u16* WT    = (u16*)(ws + 16777216);            // 6.29 MB [3072][1024]
    u16* WoT   = (u16*)(ws + 23068672);            // 2.10 MB
    u16* qkvb  = (u16*)(ws + 25165824);            // 33.55 MB [8192][2048] (Q,K only)
    u16* vT    = (u16*)(ws + 58720256);            // 16.78 MB
    u16* maskb = (u16*)(ws + 75497472);            // 8.39 MB bf16 mask
    u16* av = xn;  // xn dead after QKV GEMM

    dim3 tb(256);
    // all 4 weight transposes in one launch (z selects W; scale folds into Wq)
    transposeW<<<dim3(16, 16, 4), tb, 0, stream>>>(Wq, Wk, Wv, Wo, WT, WoT);
    maskprep<<<4096, tb, 0, stream>>>(mask, maskb);
    ln_kernel<<<8192, tb, 0, stream>>>(x, gamma, beta, xn);
    // QKV GEMM (XCD-swizzled 1D grid; Q,K -> qkvb ldc=2048; V -> vT transposed)
    gemm_bt<<<24 * 64, tb, 0, stream>>>(xn, WT, qkvb, nullptr, nullptr, 1024, 2048, 0, 24, vT);
    attn_kernel<<<dim3(16, 64), tb, 0, stream>>>(qkvb, vT, maskb, av);
    gemm_bt<<<8 * 64, tb, 0, stream>>>(av, WoT, nullptr, (float*)d_out, bo, 1024, 1024, 1, 8, nullptr);
}

// Round 16
// 238.487 us; speedup vs baseline: 1.0469x; 1.0469x over previous
//
#include <hip/hip_runtime.h>

typedef unsigned short u16;
typedef unsigned int u32;
typedef __bf16 bf16x8 __attribute__((ext_vector_type(8)));
typedef float f32x4 __attribute__((ext_vector_type(4)));

#define AS1 __attribute__((address_space(1)))
#define AS3 __attribute__((address_space(3)))

// XOR-swizzle for 128B-row LDS tiles (T2): flips byte bits 4-6 with row&7
#define SWZB(x) ((x) ^ ((((x) >> 7) & 7) << 4))

__device__ __forceinline__ float bf2f(u16 u) {
    union { u32 i; float f; } v; v.i = ((u32)u) << 16; return v.f;
}
__device__ __forceinline__ u16 f2bf(float f) {
    union { float f; u32 i; } v; v.f = f;
    u32 i = v.i;
    u32 r = (i + 0x7fffu + ((i >> 16) & 1u)) >> 16;
    return (u16)r;
}
// unpack a u32 holding two bf16: low elem -> f32, high elem -> f32
__device__ __forceinline__ float blo(u32 u) {
    union { u32 i; float f; } v; v.i = u << 16; return v.f;
}
__device__ __forceinline__ float bhi(u32 u) {
    union { u32 i; float f; } v; v.i = u & 0xFFFF0000u; return v.f;
}
__device__ __forceinline__ u32 cvtpk_bf16(float lo, float hi) {
    u32 r;
    asm("v_cvt_pk_bf16_f32 %0, %1, %2" : "=v"(r) : "v"(lo), "v"(hi));
    return r;
}
// raw 2^x (v_exp_f32); log2e pre-folded into Wq so softmax = exp2(s*m)
__device__ __forceinline__ float fexp2(float x) {
    float r;
    asm("v_exp_f32 %0, %1" : "=v"(r) : "v"(x));
    return r;
}
__device__ __forceinline__ void gload_lds16(const u16* src, u16* dst) {
    __builtin_amdgcn_global_load_lds((const AS1 void*)src, (AS3 void*)dst, 16, 0, 0);
}

// ---------------------------------------------------------------- prep
// ONE launch for all preprocessing (block-uniform branch, disjoint I/O):
//   blocks [0,1024):     4x weight transpose fp32->bf16 (scale folds into Wq)
//   blocks [1024,5120):  mask fp32->bf16
//   blocks [5120,13312): LayerNorm row kernel
__global__ __launch_bounds__(256) void prep_kernel(
    const float* __restrict__ x, const float* __restrict__ g,
    const float* __restrict__ bb, u16* __restrict__ xn,
    const float* __restrict__ mask, u16* __restrict__ maskb,
    const float* __restrict__ Wq, const float* __restrict__ Wk,
    const float* __restrict__ Wv, const float* __restrict__ Wo,
    u16* __restrict__ WT, u16* __restrict__ WoT) {
    __shared__ __align__(16) char lds[64 * 65 * 2];
    int bid = blockIdx.x;
    int tid = threadIdx.x;
    if (bid < 1024) {
        // ---- weight transpose: out[j][i] = (bf16)(in[i][j]*scale)
        u16 (*t)[65] = (u16(*)[65])lds;
        int z = bid >> 8, rem = bid & 255;
        int by = rem >> 4, bx = rem & 15;
        const float* in = (z == 0) ? Wq : (z == 1) ? Wk : (z == 2) ? Wv : Wo;
        u16* out = (z < 3) ? WT + (size_t)z * 1024 * 1024 : WoT;
        float scale = (z == 0) ? 0.18033688f : 1.0f;   // SCALE*log2e into Wq
        int c = tid & 63, r0 = tid >> 6;
        int ib = by * 64, jb = bx * 64;
        #pragma unroll
        for (int r = r0; r < 64; r += 4)
            t[r][c] = f2bf(in[(size_t)(ib + r) * 1024 + jb + c] * scale);
        __syncthreads();
        #pragma unroll
        for (int r = r0; r < 64; r += 4) out[(size_t)(jb + r) * 1024 + ib + c] = t[c][r];
    } else if (bid < 5120) {
        // ---- mask fp32 -> bf16
        int i = (bid - 1024) * 256 + tid;
        float4 v = *(const float4*)&mask[(size_t)i * 4];
        ushort4 o;
        o.x = f2bf(v.x); o.y = f2bf(v.y); o.z = f2bf(v.z); o.w = f2bf(v.w);
        *(ushort4*)&maskb[(size_t)i * 4] = o;
    } else {
        // ---- LayerNorm, one row per block
        float* red = (float*)lds;
        int row = bid - 5120;
        const float* xr = x + (size_t)row * 1024;
        float4 v = *(const float4*)&xr[tid * 4];
        float f0 = v.x, f1 = v.y, f2 = v.z, f3 = v.w;
        float s = f0 + f1 + f2 + f3;
        float sq = f0 * f0 + f1 * f1 + f2 * f2 + f3 * f3;
        #pragma unroll
        for (int m = 1; m < 64; m <<= 1) { s += __shfl_xor(s, m, 64); sq += __shfl_xor(sq, m, 64); }
        int wid = tid >> 6, lane = tid & 63;
        if (lane == 0) { red[wid] = s; red[4 + wid] = sq; }
        __syncthreads();
        s = red[0] + red[1] + red[2] + red[3];
        sq = red[4] + red[5] + red[6] + red[7];
        float mu = s * (1.f / 1024.f);
        float var = sq * (1.f / 1024.f) - mu * mu;
        float rs = rsqrtf(var + 1e-5f);
        float4 gv = *(const float4*)&g[tid * 4];
        float4 bv = *(const float4*)&bb[tid * 4];
        ushort4 o;
        o.x = f2bf((f0 - mu) * rs * gv.x + bv.x);
        o.y = f2bf((f1 - mu) * rs * gv.y + bv.y);
        o.z = f2bf((f2 - mu) * rs * gv.z + bv.z);
        o.w = f2bf((f3 - mu) * rs * gv.w + bv.w);
        *(ushort4*)&xn[(size_t)row * 1024 + tid * 4] = o;
    }
}

// ---------------------------------------------------------------- GEMM (B^T)
// C[m][n] = sum_k A[m][k]*BT[n][k]; ext=0: bf16 out; ext=1: fp32 out + bias.
// vTout != nullptr: V-column blocks (n0 >= 2048) write TRANSPOSED to
// vT[(b*1024 + (col-2048)) * 2048 + t] (fused vtrans); Q,K go to C16 with
// ldc (=2048: V-third of qkvb eliminated).
// 1D grid with XCD-slab swizzle (T1).
__global__ __launch_bounds__(256) void gemm_bt(const u16* __restrict__ A,
                                               const u16* __restrict__ BT,
                                               u16* __restrict__ C16,
                                               float* __restrict__ C32,
                                               const float* __restrict__ bias,
                                               int K, int ldc, int ext, int nbx,
                                               u16* __restrict__ vTout) {
    __shared__ __align__(16) u16 lA[128 * 32];
    __shared__ __align__(16) u16 lB[128 * 32];
    int bid = blockIdx.x;
    int xcd = bid & 7, loc = bid >> 3;
    int npx = nbx >> 3;                  // n-blocks per XCD
    int n0 = (xcd * npx + loc % npx) * 128;
    int m0 = (loc / npx) * 128;
    int tid = threadIdx.x, lane = tid & 63, wid = tid >> 6;
    int wr = wid >> 1, wc = wid & 1;
    int l4 = lane >> 4, l15 = lane & 15;

    f32x4 acc[4][4] = {};
    int NT = K >> 5;

    auto stage = [&](int kt) {
        int k0 = kt << 5;
        #pragma unroll
        for (int i = 0; i < 2; ++i) {
            int j = wid * 2 + i;
            int row = j * 16 + (lane >> 2);
            int ch = (lane & 3) * 8;
            gload_lds16(A + (size_t)(m0 + row) * K + k0 + ch, &lA[j * 512]);
            gload_lds16(BT + (size_t)(n0 + row) * K + k0 + ch, &lB[j * 512]);
        }
    };
    stage(0);
    for (int kt = 0; kt < NT; ++kt) {
        __syncthreads();
        bf16x8 af[4], bfr[4];
        #pragma unroll
        for (int i = 0; i < 4; ++i) {
            af[i]  = *(const bf16x8*)&lA[(wr * 64 + i * 16 + l15) * 32 + l4 * 8];
            bfr[i] = *(const bf16x8*)&lB[(wc * 64 + i * 16 + l15) * 32 + l4 * 8];
        }
        __syncthreads();
        if (kt + 1 < NT) stage(kt + 1);
        #pragma unroll
        for (int i = 0; i < 4; ++i)
            #pragma unroll
            for (int j = 0; j < 4; ++j)
                acc[i][j] = __builtin_amdgcn_mfma_f32_16x16x32_bf16(af[i], bfr[j], acc[i][j], 0, 0, 0);
    }
    bool vblk = (vTout != nullptr) && (n0 >= 2048);
    #pragma unroll
    for (int j = 0; j < 4; ++j) {
        int col = n0 + wc * 64 + j * 16 + l15;
        if (vblk) {
            int hd = col - 2048;
            #pragma unroll
            for (int i = 0; i < 4; ++i) {
                int trow = m0 + wr * 64 + i * 16 + l4 * 4;   // 4 consecutive t
                int bidx = trow >> 11, t = trow & 2047;
                ushort4 pk;
                pk.x = f2bf(acc[i][j][0]);
                pk.y = f2bf(acc[i][j][1]);
                pk.z = f2bf(acc[i][j][2]);
                pk.w = f2bf(acc[i][j][3]);
                *(ushort4*)&vTout[(size_t)(bidx * 1024 + hd) * 2048 + t] = pk;
            }
        } else {
            float bv = ext ? bias[col] : 0.f;
            #pragma unroll
            for (int i = 0; i < 4; ++i) {
                #pragma unroll
                for (int r = 0; r < 4; ++r) {
                    int row = m0 + wr * 64 + i * 16 + l4 * 4 + r;
                    float val = acc[i][j][r] + bv;
                    if (ext) C32[(size_t)row * ldc + col] = val;
                    else     C16[(size_t)row * ldc + col] = f2bf(val);
                }
            }
        }
    }
}

// ---------------------------------------------------------------- attention
// (R14 structure — best measured, 133 us.) Swapped QK^T + permuted K staging
// (P stays in registers), 2 q-frags/wave, 4 waves/block, QBLK=128. bf16 MASK.
// Pipelined body: QKT(t) -> exp(t) -> stage(t+1) -> load(t+2) -> PV(t) -> bar.
__global__ __launch_bounds__(256) void attn_kernel(const u16* __restrict__ qkv,
                                                   const u16* __restrict__ vT,
                                                   const u16* __restrict__ maskb,
                                                   u16* __restrict__ av) {
    __shared__ __align__(16) u16 lK[2][64 * 64];   // [kv][dh], rows permuted+swizzled
    __shared__ __align__(16) u16 lV[2][64 * 64];   // [dh][kv], swizzled
    int qt = blockIdx.x, bh = blockIdx.y;
    int b = bh >> 4, h = bh & 15;
    int tid = threadIdx.x, lane = tid & 63, wid = tid >> 6;
    int l4 = lane >> 4, l15 = lane & 15;
    int qw = qt * 128 + wid * 32;      // this wave's 32 q-rows

    const u16* qb0 = qkv + (size_t)(b * 2048 + qw + l15) * 2048 + h * 64;
    const u16* qb1 = qb0 + (size_t)16 * 2048;
    bf16x8 qf00 = *(const bf16x8*)&qb0[l4 * 8];
    bf16x8 qf01 = *(const bf16x8*)&qb0[32 + l4 * 8];
    bf16x8 qf10 = *(const bf16x8*)&qb1[l4 * 8];
    bf16x8 qf11 = *(const bf16x8*)&qb1[32 + l4 * 8];
    const u16* mrow0 = maskb + (size_t)(qw + l15) * 2048 + 8 * l4;
    const u16* mrow1 = mrow0 + (size_t)16 * 2048;

    f32x4 o0[4] = {}, o1[4] = {};
    float lsum0 = 0.f, lsum1 = 0.f;

    // staging chunks: chunk c = 16B covering row c>>3, dh/kv (c&7)*8
    int c0 = tid, c1 = 256 + tid;
    // K-row permutation: QK^T C-frag k-order == PV A-frag k-order
    auto pmap = [](int g) {
        return (g & 32) + 4 * ((g >> 3) & 3) + (g & 3) + ((g & 4) << 2);
    };
    int kd0 = SWZB(pmap(c0 >> 3) * 128 + (c0 & 7) * 16);
    int kd1 = SWZB(pmap(c1 >> 3) * 128 + (c1 & 7) * 16);
    int vd0 = SWZB((c0 >> 3) * 128 + (c0 & 7) * 16);
    int vd1 = SWZB((c1 >> 3) * 128 + (c1 & 7) * 16);
    const u16* ksrc0 = qkv + (size_t)(b * 2048 + (c0 >> 3)) * 2048 + 1024 + h * 64 + (c0 & 7) * 8;
    const u16* ksrc1 = qkv + (size_t)(b * 2048 + (c1 >> 3)) * 2048 + 1024 + h * 64 + (c1 & 7) * 8;
    const u16* vsrc0 = vT + (size_t)(bh * 64 + (c0 >> 3)) * 2048 + (c0 & 7) * 8;
    const u16* vsrc1 = vT + (size_t)(bh * 64 + (c1 >> 3)) * 2048 + (c1 & 7) * 8;

    auto loadKV = [&](int t, bf16x8& K0, bf16x8& K1, bf16x8& V0, bf16x8& V1) {
        size_t ko = (size_t)t * (64 * 2048);
        int vo = t * 64;
        K0 = *(const bf16x8*)(ksrc0 + ko);
        K1 = *(const bf16x8*)(ksrc1 + ko);
        V0 = *(const bf16x8*)(vsrc0 + vo);
        V1 = *(const bf16x8*)(vsrc1 + vo);
    };

    union PU { u32 u[4]; bf16x8 v; };

    // body: tile t lives in buf[t&1]; nxt holds tile t+1's regs (staged here);
    // free gets tile t+2's loads issued into it.
    auto body = [&](int t, int pbuf,
                    bf16x8& nK0, bf16x8& nK1, bf16x8& nV0, bf16x8& nV1,
                    bf16x8& fK0, bf16x8& fK1, bf16x8& fV0, bf16x8& fV1) {
        int k0 = t * 64;
        // bf16 mask loads for this tile: 2x16B per q-frag (cover under QK^T)
        uint4 mua0 = *(const uint4*)(mrow0 + k0);        // cols 8l4+0..7
        uint4 mub0 = *(const uint4*)(mrow0 + k0 + 32);   // cols 8l4+32..39
        uint4 mua1 = *(const uint4*)(mrow1 + k0);
        uint4 mub1 = *(const uint4*)(mrow1 + k0 + 32);
        f32x4 mm0[4], mm1[4];
        mm0[0] = f32x4{blo(mua0.x), bhi(mua0.x), blo(mua0.y), bhi(mua0.y)};
        mm0[1] = f32x4{blo(mua0.z), bhi(mua0.z), blo(mua0.w), bhi(mua0.w)};
        mm0[2] = f32x4{blo(mub0.x), bhi(mub0.x), blo(mub0.y), bhi(mub0.y)};
        mm0[3] = f32x4{blo(mub0.z), bhi(mub0.z), blo(mub0.w), bhi(mub0.w)};
        mm1[0] = f32x4{blo(mua1.x), bhi(mua1.x), blo(mua1.y), bhi(mua1.y)};
        mm1[1] = f32x4{blo(mua1.z), bhi(mua1.z), blo(mua1.w), bhi(mua1.w)};
        mm1[2] = f32x4{blo(mub1.x), bhi(mub1.x), blo(mub1.y), bhi(mub1.y)};
        mm1[3] = f32x4{blo(mub1.z), bhi(mub1.z), blo(mub1.w), bhi(mub1.w)};
        // S = mfma(K, Q)
        const char* Kb = (const char*)lK[pbuf];
        f32x4 s0[4] = {}, s1[4] = {};
        __builtin_amdgcn_s_setprio(1);
        #pragma unroll
        for (int fj = 0; fj < 4; ++fj) {
            bf16x8 kf0 = *(const bf16x8*)(Kb + SWZB((fj * 16 + l15) * 128 + l4 * 16));
            bf16x8 kf1 = *(const bf16x8*)(Kb + SWZB((fj * 16 + l15) * 128 + 64 + l4 * 16));
            s0[fj] = __builtin_amdgcn_mfma_f32_16x16x32_bf16(kf0, qf00, s0[fj], 0, 0, 0);
            s0[fj] = __builtin_amdgcn_mfma_f32_16x16x32_bf16(kf1, qf01, s0[fj], 0, 0, 0);
            s1[fj] = __builtin_amdgcn_mfma_f32_16x16x32_bf16(kf0, qf10, s1[fj], 0, 0, 0);
            s1[fj] = __builtin_amdgcn_mfma_f32_16x16x32_bf16(kf1, qf11, s1[fj], 0, 0, 0);
        }
        __builtin_amdgcn_s_setprio(0);
        // P = exp2(s*m) (SCALE*log2e in Q), packed into PV A-frags
        PU pa0[2], pa1[2];
        #pragma unroll
        for (int fj = 0; fj < 4; ++fj) {
            float p0 = fexp2(s0[fj][0] * mm0[fj][0]);
            float p1 = fexp2(s0[fj][1] * mm0[fj][1]);
            float p2 = fexp2(s0[fj][2] * mm0[fj][2]);
            float p3 = fexp2(s0[fj][3] * mm0[fj][3]);
            lsum0 += (p0 + p1) + (p2 + p3);
            int ks = fj >> 1, hf = (fj & 1) * 2;
            pa0[ks].u[hf]     = cvtpk_bf16(p0, p1);
            pa0[ks].u[hf + 1] = cvtpk_bf16(p2, p3);
        }
        #pragma unroll
        for (int fj = 0; fj < 4; ++fj) {
            float p0 = fexp2(s1[fj][0] * mm1[fj][0]);
            float p1 = fexp2(s1[fj][1] * mm1[fj][1]);
            float p2 = fexp2(s1[fj][2] * mm1[fj][2]);
            float p3 = fexp2(s1[fj][3] * mm1[fj][3]);
            lsum1 += (p0 + p1) + (p2 + p3);
            int ks = fj >> 1, hf = (fj & 1) * 2;
            pa1[ks].u[hf]     = cvtpk_bf16(p0, p1);
            pa1[ks].u[hf + 1] = cvtpk_bf16(p2, p3);
        }
        // stage tile t+1 into the other buffer (its last readers passed bar(t-1))
        if (t + 1 < 32) {
            char* Kn = (char*)lK[pbuf ^ 1];
            char* Vn = (char*)lV[pbuf ^ 1];
            *(bf16x8*)(Kn + kd0) = nK0;
            *(bf16x8*)(Kn + kd1) = nK1;
            *(bf16x8*)(Vn + vd0) = nV0;
            *(bf16x8*)(Vn + vd1) = nV1;
        }
        // issue tile t+2 loads (in flight across PV + bar + QKT(t+1))
        if (t + 2 < 32) loadKV(t + 2, fK0, fK1, fV0, fV1);
        // O += P V
        const char* Vb = (const char*)lV[pbuf];
        __builtin_amdgcn_s_setprio(1);
        #pragma unroll
        for (int ks = 0; ks < 2; ++ks) {
            #pragma unroll
            for (int fj = 0; fj < 4; ++fj) {
                bf16x8 vf = *(const bf16x8*)(Vb + SWZB((fj * 16 + l15) * 128 + ks * 64 + l4 * 16));
                o0[fj] = __builtin_amdgcn_mfma_f32_16x16x32_bf16(pa0[ks].v, vf, o0[fj], 0, 0, 0);
                o1[fj] = __builtin_amdgcn_mfma_f32_16x16x32_bf16(pa1[ks].v, vf, o1[fj], 0, 0, 0);
            }
        }
        __builtin_amdgcn_s_setprio(0);
        __syncthreads();  // tile t+1 staged & visible; buffers rotate
    };

    bf16x8 ka0, ka1, va0, va1, kb0, kb1, vb0, vb1;
    // prologue: tile0 -> buf0, tile1 regs in flight
    loadKV(0, ka0, ka1, va0, va1);
    *(bf16x8*)((char*)lK[0] + kd0) = ka0;
    *(bf16x8*)((char*)lK[0] + kd1) = ka1;
    *(bf16x8*)((char*)lV[0] + vd0) = va0;
    *(bf16x8*)((char*)lV[0] + vd1) = va1;
    loadKV(1, kb0, kb1, vb0, vb1);
    __syncthreads();
    for (int t = 0; t < 32; t += 2) {
        body(t,     0, kb0, kb1, vb0, vb1, ka0, ka1, va0, va1);
        body(t + 1, 1, ka0, ka1, va0, va1, kb0, kb1, vb0, vb1);
    }

    // rowsums: reduce over the 4 l4-groups (same q=l15 column)
    lsum0 += __shfl_xor(lsum0, 16, 64);
    lsum0 += __shfl_xor(lsum0, 32, 64);
    lsum1 += __shfl_xor(lsum1, 16, 64);
    lsum1 += __shfl_xor(lsum1, 32, 64);
    float den0[4], den1[4];
    #pragma unroll
    for (int r = 0; r < 4; ++r) {
        den0[r] = __shfl(lsum0, l4 * 4 + r, 64);
        den1[r] = __shfl(lsum1, l4 * 4 + r, 64);
    }
    #pragma unroll
    for (int fj = 0; fj < 4; ++fj) {
        #pragma unroll
        for (int r = 0; r < 4; ++r) {
            int col = h * 64 + fj * 16 + l15;
            av[(size_t)(b * 2048 + qw + l4 * 4 + r) * 1024 + col]      = f2bf(o0[fj][r] / den0[r]);
            av[(size_t)(b * 2048 + qw + 16 + l4 * 4 + r) * 1024 + col] = f2bf(o1[fj][r] / den1[r]);
        }
    }
}

// ---------------------------------------------------------------- launch
extern "C" void kernel_launch(void* const* d_in, const int* in_sizes, int n_in,
                              void* d_out, int out_size, void* d_ws, size_t ws_size,
                              hipStream_t stream) {
    (void)in_sizes; (void)n_in; (void)out_size; (void)ws_size;
    const float* x     = (const float*)d_in[0];
    const float* mask  = (const float*)d_in[1];
    const float* gamma = (const float*)d_in[2];
    const float* beta  = (const float*)d_in[3];
    const float* Wq    = (const float*)d_in[4];
    const float* Wk    = (const float*)d_in[5];
    const float* Wv    = (const float*)d_in[6];
    const float* Wo    = (const float*)d_in[7];
    const float* bo    = (const float*)d_in[8];

    char* ws = (char*)d_ws;
    u16* xn    = (u16*)(ws);                       // 16.8 MB (reused as av)
    u16* WT    = (u16*)(ws + 16777216);            // 6.29 MB [3072][1024]
    u16* WoT   = (u16*)(ws + 23068672);            // 2.10 MB
    u16* qkvb  = (u16*)(ws + 25165824);            // 33.55 MB [8192][2048] (Q,K only)
    u16* vT    = (u16*)(ws + 58720256);            // 16.78 MB
    u16* maskb = (u16*)(ws + 75497472);            // 8.39 MB bf16 mask
    u16* av = xn;  // xn dead after QKV GEMM

    dim3 tb(256);
    // one prep launch: weight transposes + mask->bf16 + LayerNorm
    prep_kernel<<<13312, tb, 0, stream>>>(x, gamma, beta, xn, mask, maskb,
                                          Wq, Wk, Wv, Wo, WT, WoT);
    // QKV GEMM (XCD-swizzled 1D grid; Q,K -> qkvb ldc=2048; V -> vT transposed)
    gemm_bt<<<24 * 64, tb, 0, stream>>>(xn, WT, qkvb, nullptr, nullptr, 1024, 2048, 0, 24, vT);
    attn_kernel<<<dim3(16, 64), tb, 0, stream>>>(qkvb, vT, maskb, av);
    gemm_bt<<<8 * 64, tb, 0, stream>>>(av, WoT, nullptr, (float*)d_out, bo, 1024, 1024, 1, 8, nullptr);
}